// Round 8
// baseline (63.998 us; speedup 1.0000x reference)
//
#include <hip/hip_runtime.h>
#include <math.h>

// SpikeMLP: 2-layer spiking MLP, batch=128, in=800, hid=128, out=10.
//
// Trajectory: R3 66us (1 wave/CU latency-bound) -> R5 two-kernel 76.9 total
// -> R6 fused spin-wait REGRESSED (device-scope fences thrash L2 cross-XCD;
// reverted) -> R7 62.1us (1024 blocks, 16 lanes/neuron, closed-form
// crossing). Fixed harness floor ~50us (256MB 0xAA ws-poison fill = 40us +
// input restore + node gaps); controllable share now ~12us.
//
// R8: push occupancy/ILP further on k1: 2048 blocks (b=blk>>4, q=blk&15,
// 8 neurons/block, 32 lanes/neuron) -> 8 blocks/CU = 32 waves/CU (max),
// per-lane chain = 7 independent float4 loads (6 full + tail), all in
// flight. LDS 6.4KB/block -> 8 blocks fit easily. k2 unchanged.
//
// Layer-1 math (verified R3-R7): for t>=256 (the only finite-threshold
// steps) every finite ti < 1.0 <= t*DT, so mem(t) = t*DT*S - A with
// S=sum(W1[n,i]), A=sum(ti*W1[n,i]) over finite ti. mem(511)>0 gates
// spiking; first crossing of mem(t) > (511-t)*DT is closed-form:
// t > (A+511*DT)/(DT*(S+1)) for S+1>0, else t=256.
// Layer-2: v(t) = t*S2 - A2 linear (no relu) -> endpoint guard, faithful
// per-step loop only if v can approach 20. "No spike" sentinel = 1e30f
// (bf16-finite; harness compares in bf16 -> FLT_MAX/inf gives nan-fail).

#define DT (1.0f / 256.0f)
#define NSTEP 256
#define TSTEPS 512
#define IN_DIM 800
#define HID 128
#define OUT_DIM 10
#define NOSPIKE 1e30f

// ---------------- kernel 1: hidden spike times -> ws[b*128+n] -------------
// 2048 blocks: b = blk>>4, q = blk&15; neuron n = q*8 + (tid>>5),
// slice s = tid&31 covers i = k*128 + s*4 (+3), k=0..5, tail 768+s*4 (s<8).
__global__ __launch_bounds__(256) void spike_hidden(
    const float* __restrict__ x,    // [128, 800]
    const float* __restrict__ W1,   // [128, 800]
    float* __restrict__ hs_out)     // [128, 128]
{
    const int b   = blockIdx.x >> 4;
    const int q   = blockIdx.x & 15;
    const int tid = threadIdx.x;
    const int n   = q * 8 + (tid >> 5);    // hidden neuron
    const int s   = tid & 31;              // slice 0..31

    __shared__ float xm[IN_DIM];   // masked x: ti if finite else 0
    __shared__ float mk[IN_DIM];   // mask:     1  if finite else 0

    // stage x row into LDS (coalesced)
    const float* xr = x + (size_t)b * IN_DIM;
    for (int i = tid; i < IN_DIM; i += 256) {
        float xi = xr[i];
        float m  = (xi != 1.0f) ? 1.0f : 0.0f;
        xm[i] = m * xi;
        mk[i] = m;
    }
    __syncthreads();

    const float* wr = W1 + (size_t)n * IN_DIM;
    float S = 0.0f;   // sum of W1[n,i] over finite inputs
    float A = 0.0f;   // sum of ti * W1[n,i] over finite inputs
#pragma unroll
    for (int k = 0; k < 6; ++k) {                  // 6 x 128 = 768 elems
        const int i = k * 128 + s * 4;
        float4 wv = *(const float4*)(wr + i);
        float4 xv = *(const float4*)(&xm[i]);
        float4 mv = *(const float4*)(&mk[i]);
        S = fmaf(mv.x, wv.x, S);  A = fmaf(xv.x, wv.x, A);
        S = fmaf(mv.y, wv.y, S);  A = fmaf(xv.y, wv.y, A);
        S = fmaf(mv.z, wv.z, S);  A = fmaf(xv.z, wv.z, A);
        S = fmaf(mv.w, wv.w, S);  A = fmaf(xv.w, wv.w, A);
    }
    if (s < 8) {                                   // tail: elems 768..799
        const int i = 768 + s * 4;
        float4 wv = *(const float4*)(wr + i);
        float4 xv = *(const float4*)(&xm[i]);
        float4 mv = *(const float4*)(&mk[i]);
        S = fmaf(mv.x, wv.x, S);  A = fmaf(xv.x, wv.x, A);
        S = fmaf(mv.y, wv.y, S);  A = fmaf(xv.y, wv.y, A);
        S = fmaf(mv.z, wv.z, S);  A = fmaf(xv.z, wv.z, A);
        S = fmaf(mv.w, wv.w, S);  A = fmaf(xv.w, wv.w, A);
    }
    // reduce across the 32 slices (same wave)
    S += __shfl_xor(S, 1);   A += __shfl_xor(A, 1);
    S += __shfl_xor(S, 2);   A += __shfl_xor(A, 2);
    S += __shfl_xor(S, 4);   A += __shfl_xor(A, 4);
    S += __shfl_xor(S, 8);   A += __shfl_xor(A, 8);
    S += __shfl_xor(S, 16);  A += __shfl_xor(A, 16);

    if (s == 0) {
        // first t in [256,511] with t*DT*S - A > (511-t)*DT, given
        // mem(511) > 0; closed form: t > (A + 511*DT) / (DT*(S+1)).
        float h;
        float mem_last = fmaf(511.0f * DT, S, -A);
        if (!(mem_last > 0.0f)) {
            h = 1.0f;                        // no spike -> sentinel 1.0
        } else {
            float Sp = S + 1.0f;
            int tf;
            if (!(Sp > 0.0f)) {
                tf = NSTEP;                  // lhs-rhs decreasing -> first step
            } else {
                float X = (A + 511.0f * DT) / (DT * Sp);
                tf = (int)floorf(X) + 1;     // smallest integer t with t > X
                if (tf < NSTEP)      tf = NSTEP;
                if (tf > TSTEPS - 1) tf = TSTEPS - 1;
            }
            h = (float)tf * DT - 1.0f;       // exact in fp32
        }
        hs_out[b * HID + n] = h;
    }
}

// ---------------- kernel 2: output spike times ----------------------------
// 128 blocks (one per b) x 640 threads; wave o = tid>>6 (0..9).
__global__ __launch_bounds__(640) void spike_out(
    const float* __restrict__ hs,   // [128, 128]
    const float* __restrict__ W2,   // [10, 128]
    float* __restrict__ out)        // [128, 10]
{
    const int b   = blockIdx.x;
    const int tid = threadIdx.x;
    const int o   = tid >> 6;
    const int j   = tid & 63;

    const float* hr = hs + (size_t)b * HID;
    const float* w2 = W2 + (size_t)o * HID;

    float S2 = 0.0f, A2 = 0.0f;
#pragma unroll
    for (int i = j; i < HID; i += 64) {        // 2 iterations
        float hi = hr[i];
        float w  = w2[i];
        float m  = (hi != 1.0f) ? 1.0f : 0.0f; // h==1 -> INF -> excluded
        S2 = fmaf(m, w, S2);
        A2 = fmaf(m * hi, w, A2);
    }
#pragma unroll
    for (int msk = 1; msk < 64; msk <<= 1) {
        S2 += __shfl_xor(S2, msk);
        A2 += __shfl_xor(A2, msk);
    }
    if (j == 0) {
        // v(t) = t*S2 - A2, t = 1 + k*DT, k in [0,1024): linear ->
        // endpoint guard; faithful loop only if near the 20.0 threshold.
        float res = NOSPIKE;
        float v_lo = fmaf(1.0f,                S2, -A2);
        float v_hi = fmaf(1.0f + 1023.0f * DT, S2, -A2);
        if (fmaxf(v_lo, v_hi) > 19.999f) {
            for (int k = 0; k < 1024; ++k) {
                float t = fmaf((float)k, DT, 1.0f);   // exact fp32
                float v = fmaf(t, S2, -A2);
                if (v > 20.0f) { res = t; break; }
            }
        }
        out[b * OUT_DIM + o] = res;
    }
}

extern "C" void kernel_launch(void* const* d_in, const int* in_sizes, int n_in,
                              void* d_out, int out_size, void* d_ws, size_t ws_size,
                              hipStream_t stream) {
    const float* x  = (const float*)d_in[0];   // (128, 800)
    const float* W1 = (const float*)d_in[1];   // (128, 800)
    const float* W2 = (const float*)d_in[2];   // (10, 128)
    float* out = (float*)d_out;                // (128, 10)
    float* hs  = (float*)d_ws;                 // 128*128 f32 scratch

    spike_hidden<<<2048, 256, 0, stream>>>(x, W1, hs);
    spike_out<<<128, 640, 0, stream>>>(hs, W2, out);
}

// Round 9
// 62.047 us; speedup vs baseline: 1.0314x; 1.0314x over previous
//
#include <hip/hip_runtime.h>
#include <math.h>

// SpikeMLP: 2-layer spiking MLP, batch=128, in=800, hid=128, out=10.
//
// Trajectory: R3 66us (1 wave/CU latency-bound) -> R5 two-kernel split ->
// R6 fused spin-wait REGRESSED (cross-XCD fences, 77us kernel; reverted) ->
// R7 62.1us BEST (1024 blocks, 16 lanes/neuron, closed-form crossing) ->
// R8 2048 blocks/32 lanes REGRESSED to 64.0us (2x redundant x staging,
// tail divergence; occupancy benefit saturated at 16 waves/CU).
// R9 = exact revert to R7 (empirical optimum).
//
// Budget: ~40us harness ws-poison fill (256MB @ 6.7TB/s, untouchable) +
// ~10us other harness reset nodes/gaps + ~12us our k1+k2 incl. launch gaps.
// k1 throughput floor ~2us (52MB W1 @ L2 BW); rest is launch/latency that
// R6 (fusion) and R8 (occupancy) proved can't be removed.
//
// Layer-1 math (verified R3-R8): for t>=256 (the only finite-threshold
// steps) every finite ti < 1.0 <= t*DT, so mem(t) = t*DT*S - A with
// S=sum(W1[n,i]), A=sum(ti*W1[n,i]) over finite ti. mem(511)>0 gates
// spiking; first crossing of mem(t) > (511-t)*DT is closed-form:
// t > (A+511*DT)/(DT*(S+1)) for S+1>0, else t=256.
// Layer-2: v(t) = t*S2 - A2 linear (no relu) -> endpoint guard, faithful
// per-step loop only if v can approach 20. "No spike" sentinel = 1e30f
// (bf16-finite; harness compares in bf16 -> FLT_MAX/inf gives nan-fail).

#define DT (1.0f / 256.0f)
#define NSTEP 256
#define TSTEPS 512
#define IN_DIM 800
#define HID 128
#define OUT_DIM 10
#define NOSPIKE 1e30f

// ---------------- kernel 1: hidden spike times -> ws[b*128+n] -------------
// 1024 blocks: b = blk>>3, q = blk&7; neurons n = q*16 + (tid>>4),
// slice s = tid&15 covers i = k*64 + s*4 (+3), k = 0..11, tail 768+s*4 (s<8).
__global__ __launch_bounds__(256) void spike_hidden(
    const float* __restrict__ x,    // [128, 800]
    const float* __restrict__ W1,   // [128, 800]
    float* __restrict__ hs_out)     // [128, 128]
{
    const int b   = blockIdx.x >> 3;
    const int q   = blockIdx.x & 7;
    const int tid = threadIdx.x;
    const int n   = q * 16 + (tid >> 4);   // hidden neuron
    const int s   = tid & 15;              // slice 0..15

    __shared__ float xm[IN_DIM];   // masked x: ti if finite else 0
    __shared__ float mk[IN_DIM];   // mask:     1  if finite else 0

    // stage x row into LDS (coalesced)
    const float* xr = x + (size_t)b * IN_DIM;
    for (int i = tid; i < IN_DIM; i += 256) {
        float xi = xr[i];
        float m  = (xi != 1.0f) ? 1.0f : 0.0f;
        xm[i] = m * xi;
        mk[i] = m;
    }
    __syncthreads();

    const float* wr = W1 + (size_t)n * IN_DIM;
    float S = 0.0f;   // sum of W1[n,i] over finite inputs
    float A = 0.0f;   // sum of ti * W1[n,i] over finite inputs
#pragma unroll
    for (int k = 0; k < 12; ++k) {                 // 12 x 64 = 768 elems
        const int i = k * 64 + s * 4;
        float4 wv = *(const float4*)(wr + i);
        float4 xv = *(const float4*)(&xm[i]);
        float4 mv = *(const float4*)(&mk[i]);
        S = fmaf(mv.x, wv.x, S);  A = fmaf(xv.x, wv.x, A);
        S = fmaf(mv.y, wv.y, S);  A = fmaf(xv.y, wv.y, A);
        S = fmaf(mv.z, wv.z, S);  A = fmaf(xv.z, wv.z, A);
        S = fmaf(mv.w, wv.w, S);  A = fmaf(xv.w, wv.w, A);
    }
    if (s < 8) {                                   // tail: elems 768..799
        const int i = 768 + s * 4;
        float4 wv = *(const float4*)(wr + i);
        float4 xv = *(const float4*)(&xm[i]);
        float4 mv = *(const float4*)(&mk[i]);
        S = fmaf(mv.x, wv.x, S);  A = fmaf(xv.x, wv.x, A);
        S = fmaf(mv.y, wv.y, S);  A = fmaf(xv.y, wv.y, A);
        S = fmaf(mv.z, wv.z, S);  A = fmaf(xv.z, wv.z, A);
        S = fmaf(mv.w, wv.w, S);  A = fmaf(xv.w, wv.w, A);
    }
    // reduce across the 16 slices (same wave)
    S += __shfl_xor(S, 1);  A += __shfl_xor(A, 1);
    S += __shfl_xor(S, 2);  A += __shfl_xor(A, 2);
    S += __shfl_xor(S, 4);  A += __shfl_xor(A, 4);
    S += __shfl_xor(S, 8);  A += __shfl_xor(A, 8);

    if (s == 0) {
        // first t in [256,511] with t*DT*S - A > (511-t)*DT, given
        // mem(511) > 0; closed form: t > (A + 511*DT) / (DT*(S+1)).
        float h;
        float mem_last = fmaf(511.0f * DT, S, -A);
        if (!(mem_last > 0.0f)) {
            h = 1.0f;                        // no spike -> sentinel 1.0
        } else {
            float Sp = S + 1.0f;
            int tf;
            if (!(Sp > 0.0f)) {
                tf = NSTEP;                  // lhs-rhs decreasing -> first step
            } else {
                float X = (A + 511.0f * DT) / (DT * Sp);
                tf = (int)floorf(X) + 1;     // smallest integer t with t > X
                if (tf < NSTEP)      tf = NSTEP;
                if (tf > TSTEPS - 1) tf = TSTEPS - 1;
            }
            h = (float)tf * DT - 1.0f;       // exact in fp32
        }
        hs_out[b * HID + n] = h;
    }
}

// ---------------- kernel 2: output spike times ----------------------------
// 128 blocks (one per b) x 640 threads; wave o = tid>>6 (0..9).
__global__ __launch_bounds__(640) void spike_out(
    const float* __restrict__ hs,   // [128, 128]
    const float* __restrict__ W2,   // [10, 128]
    float* __restrict__ out)        // [128, 10]
{
    const int b   = blockIdx.x;
    const int tid = threadIdx.x;
    const int o   = tid >> 6;
    const int j   = tid & 63;

    const float* hr = hs + (size_t)b * HID;
    const float* w2 = W2 + (size_t)o * HID;

    float S2 = 0.0f, A2 = 0.0f;
#pragma unroll
    for (int i = j; i < HID; i += 64) {        // 2 iterations
        float hi = hr[i];
        float w  = w2[i];
        float m  = (hi != 1.0f) ? 1.0f : 0.0f; // h==1 -> INF -> excluded
        S2 = fmaf(m, w, S2);
        A2 = fmaf(m * hi, w, A2);
    }
#pragma unroll
    for (int msk = 1; msk < 64; msk <<= 1) {
        S2 += __shfl_xor(S2, msk);
        A2 += __shfl_xor(A2, msk);
    }
    if (j == 0) {
        // v(t) = t*S2 - A2, t = 1 + k*DT, k in [0,1024): linear ->
        // endpoint guard; faithful loop only if near the 20.0 threshold.
        float res = NOSPIKE;
        float v_lo = fmaf(1.0f,                S2, -A2);
        float v_hi = fmaf(1.0f + 1023.0f * DT, S2, -A2);
        if (fmaxf(v_lo, v_hi) > 19.999f) {
            for (int k = 0; k < 1024; ++k) {
                float t = fmaf((float)k, DT, 1.0f);   // exact fp32
                float v = fmaf(t, S2, -A2);
                if (v > 20.0f) { res = t; break; }
            }
        }
        out[b * OUT_DIM + o] = res;
    }
}

extern "C" void kernel_launch(void* const* d_in, const int* in_sizes, int n_in,
                              void* d_out, int out_size, void* d_ws, size_t ws_size,
                              hipStream_t stream) {
    const float* x  = (const float*)d_in[0];   // (128, 800)
    const float* W1 = (const float*)d_in[1];   // (128, 800)
    const float* W2 = (const float*)d_in[2];   // (10, 128)
    float* out = (float*)d_out;                // (128, 10)
    float* hs  = (float*)d_ws;                 // 128*128 f32 scratch

    spike_hidden<<<1024, 256, 0, stream>>>(x, W1, hs);
    spike_out<<<128, 640, 0, stream>>>(hs, W2, out);
}